// Round 2
// baseline (251.184 us; speedup 1.0000x reference)
//
#include <hip/hip_runtime.h>
#include <cstdint>

// Y[m,n] = scale[n]*sum_k x[m,k]*(q[n,k]-zp[n]) + bias[n];  M=N=K=4096.
// int8 path: q' = q-128 (int8, exact); xq = round(x*127/6) clamped (int8).
// Y = scale_n*( sx*acc[m,n] + (128-zp_n)*Sx[m] ) + bias_n,
//   acc = sum xq*q' (EXACT int32 via mfma_i32_16x16x64_i8), Sx = exact fp32
//   row-sum of x. Only error: x quantization.
//
// R2: read-ahead pipeline. 256x256 tile, BK=64, 8 waves (2M x 4N), wave
//   tile 128x64. LDS = 3 slots x (A 16K + B 16K) = 96 KiB, triple-buffered
//   so staging of tile t+2 overlaps compute of tile t with counted
//   s_waitcnt vmcnt(2) (never 0 in steady state). Fragment reads for the
//   NEXT phase are issued before the current phase's MFMA cluster and
//   drained with counted lgkmcnt -> LDS pipe runs under the MFMA pipe.
//   setprio(1) around MFMA, sched_barrier after each counted wait (rule 18).

#define M_DIM 4096
#define N_DIM 4096
#define K_DIM 4096

typedef int v4i __attribute__((ext_vector_type(4)));

#define XQ_F 21.1666667f      // 127/6
#define XQ_INV 0.0472440945f  // 6/127

static __device__ __forceinline__ void load_lds16(const void* g, void* l) {
    __builtin_amdgcn_global_load_lds(
        (__attribute__((address_space(1))) void*)(uintptr_t)g,
        (__attribute__((address_space(3))) void*)(uint32_t)(uintptr_t)l,
        16, 0, 0);
}

static __device__ __forceinline__ int q8(float v) {
    float r = rintf(v * XQ_F);
    r = fmaxf(-127.f, fminf(127.f, r));
    return (int)r;
}
static __device__ __forceinline__ unsigned pack4(int a, int b, int c, int d) {
    return (unsigned)(a & 255) | ((unsigned)(b & 255) << 8) |
           ((unsigned)(c & 255) << 16) | ((unsigned)(d & 255) << 24);
}

// ---- prep: block b<4096 -> x row b (quantize + exact rowsum);
//            b>=4096 -> q row b-4096 (q-128 -> int8). 16 elems/thread.
__global__ __launch_bounds__(256) void prep_k(const float4* __restrict__ x,
                                              const int4* __restrict__ q,
                                              unsigned* __restrict__ xq,
                                              unsigned* __restrict__ qp,
                                              float* __restrict__ Sx) {
    const int tid = threadIdx.x;
    if (blockIdx.x < 4096) {
        const int m = blockIdx.x;
        const float4* row = x + (size_t)m * 1024;
        unsigned* orow = xq + (size_t)m * 1024;
        float s = 0.f;
        #pragma unroll
        for (int i = 0; i < 4; ++i) {
            const int idx = tid + 256 * i;
            const float4 v = row[idx];
            s += v.x + v.y + v.z + v.w;
            orow[idx] = pack4(q8(v.x), q8(v.y), q8(v.z), q8(v.w));
        }
        #pragma unroll
        for (int off = 32; off > 0; off >>= 1)
            s += __shfl_down(s, off);
        __shared__ float red[4];
        if ((tid & 63) == 0) red[tid >> 6] = s;
        __syncthreads();
        if (tid == 0) Sx[m] = red[0] + red[1] + red[2] + red[3];
    } else {
        const int n = blockIdx.x - 4096;
        const int4* row = q + (size_t)n * 1024;
        unsigned* orow = qp + (size_t)n * 1024;
        #pragma unroll
        for (int i = 0; i < 4; ++i) {
            const int idx = tid + 256 * i;
            const int4 v = row[idx];
            orow[idx] = pack4(v.x - 128, v.y - 128, v.z - 128, v.w - 128);
        }
    }
}

// LDS slot layout (32 KiB per slot, 3 slots):
//   A[256 rows x 64 B] at slot+0, B[256 x 64] at slot+16384.
//   Row = 64 B = 4 x 16B chunks; XOR swizzle: (row, logical chunk c) at
//   byte row*64 + ((c ^ (row&3)) * 16). Staging dest flat (tid*16),
//   global source chunk pre-permuted -> coalescing intact, reads
//   conflict-minimal (each bank hit exactly 8x per wave ds_read_b128).
//
// Per-tile schedule (t: 0..63, slot = t%3):
//  W0: barrier | read af1 (A rows 64-127 of wave) | stage A rounds of t+2
//      | lgkm(4) [drains af0/bf] | 16 MFMA (af0,bf -> acc[0..3][*])
//  W1: vmcnt(2) [t+1 landed; t+2's A-rounds still in flight] | barrier
//      | read af0n/bfn of t+1 | stage B rounds of t+2 | lgkm(8) [drains af1]
//      | 16 MFMA (af1,bf -> acc[4..7][*])
__device__ __forceinline__ void tile_body(
    int t, char* lds, int& sC,
    int rowAoff, int rowBoff, int off, int ldsT,
    const char*& gA0, const char*& gA1,
    const char*& gB0, const char*& gB1,
    v4i (&af0)[4], v4i (&bf)[4],
    v4i (&af0n)[4], v4i (&bfn)[4],
    v4i (&af1)[4], v4i (&acc)[8][4])
{
    const int sN = (sC == 65536) ? 0 : sC + 32768;   // slot of t+1
    const int sS = (sN == 65536) ? 0 : sN + 32768;   // slot of t+2 (= t-1, freed)

    // ---------------- W0 ----------------
    __builtin_amdgcn_s_barrier();
    #pragma unroll
    for (int i = 0; i < 4; ++i)
        af1[i] = *(const v4i*)(lds + sC + rowAoff + (i + 4) * 1024 + off);
    if (t < 62) {
        load_lds16(gA0, lds + sS +    0 + ldsT);
        load_lds16(gA1, lds + sS + 8192 + ldsT);
    }
    asm volatile("s_waitcnt lgkmcnt(4)" ::: "memory");
    __builtin_amdgcn_sched_barrier(0);
    __builtin_amdgcn_s_setprio(1);
    #pragma unroll
    for (int i = 0; i < 4; ++i)
        #pragma unroll
        for (int j = 0; j < 4; ++j)
            acc[i][j] = __builtin_amdgcn_mfma_i32_16x16x64_i8(
                af0[i], bf[j], acc[i][j], 0, 0, 0);
    __builtin_amdgcn_s_setprio(0);

    // ---------------- W1 ----------------
    if (t < 62) asm volatile("s_waitcnt vmcnt(2)" ::: "memory");
    else        asm volatile("s_waitcnt vmcnt(0)" ::: "memory");
    __builtin_amdgcn_s_barrier();
    if (t < 63) {
        #pragma unroll
        for (int i = 0; i < 4; ++i)
            af0n[i] = *(const v4i*)(lds + sN + rowAoff + i * 1024 + off);
        #pragma unroll
        for (int j = 0; j < 4; ++j)
            bfn[j] = *(const v4i*)(lds + sN + 16384 + rowBoff + j * 1024 + off);
    }
    if (t < 62) {
        load_lds16(gB0, lds + sS + 16384 + ldsT);
        load_lds16(gB1, lds + sS + 24576 + ldsT);
        gA0 += 64; gA1 += 64; gB0 += 64; gB1 += 64;
    }
    if (t < 63) asm volatile("s_waitcnt lgkmcnt(8)" ::: "memory");
    else        asm volatile("s_waitcnt lgkmcnt(0)" ::: "memory");
    __builtin_amdgcn_sched_barrier(0);
    __builtin_amdgcn_s_setprio(1);
    #pragma unroll
    for (int i = 0; i < 4; ++i)
        #pragma unroll
        for (int j = 0; j < 4; ++j)
            acc[i + 4][j] = __builtin_amdgcn_mfma_i32_16x16x64_i8(
                af1[i], bf[j], acc[i + 4][j], 0, 0, 0);
    __builtin_amdgcn_s_setprio(0);
    sC = sN;
}

__global__ __launch_bounds__(512, 2) void gemm_i8(
    const char* __restrict__ A, const char* __restrict__ B,
    const float* __restrict__ scales, const int* __restrict__ zp,
    const float* __restrict__ bias, const float* __restrict__ Sx,
    float* __restrict__ C)
{
    extern __shared__ char lds[];   // 98304 = 3 x (A 16K + B 16K)

    const int tid  = threadIdx.x;
    const int lane = tid & 63;
    const int wave = tid >> 6;
    const int wr = wave >> 2;        // 0..1 over M (128 rows each)
    const int wc = wave & 3;         // 0..3 over N (64 cols each)

    // XCD swizzle: 16x16 tile grid; XCD x -> 4(M) x 8(N) tile rectangle
    // (A 4 MiB + B 8 MiB footprint per XCD). Bijective for 256 blocks.
    const int bid = blockIdx.x;
    const int xcd = bid & 7;
    const int loc = bid >> 3;            // 0..31
    const int tileM = (xcd & 3) * 4 + (loc & 3);
    const int tileN = (xcd >> 2) * 8 + (loc >> 2);
    const int mBase = tileM * 256;
    const int nBase = tileN * 256;

    // staging: thread tid -> row tid>>2 of the 128-row round, chunk tid&3;
    // global source chunk pre-swizzled: logical = (tid&3)^((tid>>2)&3)
    const int rowR = tid >> 2;                        // 0..127
    const int lcS  = ((tid & 3) ^ (rowR & 3)) * 16;   // bytes
    const char* gA0 = A + (size_t)(mBase +   0 + rowR) * K_DIM + lcS;
    const char* gA1 = A + (size_t)(mBase + 128 + rowR) * K_DIM + lcS;
    const char* gB0 = B + (size_t)(nBase +   0 + rowR) * K_DIM + lcS;
    const char* gB1 = B + (size_t)(nBase + 128 + rowR) * K_DIM + lcS;
    const int ldsT = tid * 16;

    // frag reads: row stride 64 B; K-chunk = quad, phys = quad^(row&3)
    const int quad = lane >> 4;
    const int r16  = lane & 15;
    const int off  = (quad ^ (r16 & 3)) * 16;
    const int rowAoff = (wr * 128 + r16) * 64;   // + i*1024 (16-row blocks)
    const int rowBoff = (wc *  64 + r16) * 64;   // + j*1024, region +16384

    v4i acc[8][4];
    #pragma unroll
    for (int i = 0; i < 8; ++i)
        #pragma unroll
        for (int j = 0; j < 4; ++j)
            acc[i][j] = v4i{0, 0, 0, 0};

    // ---- prologue: stage tile0 -> slot0, tile1 -> slot1 ----
    load_lds16(gA0, lds +     0 + ldsT);
    load_lds16(gA1, lds +  8192 + ldsT);
    load_lds16(gB0, lds + 16384 + ldsT);
    load_lds16(gB1, lds + 24576 + ldsT);
    gA0 += 64; gA1 += 64; gB0 += 64; gB1 += 64;
    load_lds16(gA0, lds + 32768 +     0 + ldsT);
    load_lds16(gA1, lds + 32768 +  8192 + ldsT);
    load_lds16(gB0, lds + 32768 + 16384 + ldsT);
    load_lds16(gB1, lds + 32768 + 24576 + ldsT);
    gA0 += 64; gA1 += 64; gB0 += 64; gB1 += 64;
    asm volatile("s_waitcnt vmcnt(4)" ::: "memory");   // tile0 landed
    __builtin_amdgcn_s_barrier();

    v4i af0A[4], bfA[4], af0B[4], bfB[4], af1[4];
    #pragma unroll
    for (int i = 0; i < 4; ++i)
        af0A[i] = *(const v4i*)(lds + rowAoff + i * 1024 + off);
    #pragma unroll
    for (int j = 0; j < 4; ++j)
        bfA[j] = *(const v4i*)(lds + 16384 + rowBoff + j * 1024 + off);

    int sC = 0;
    for (int t = 0; t < 64; t += 2) {
        tile_body(t,     lds, sC, rowAoff, rowBoff, off, ldsT,
                  gA0, gA1, gB0, gB1, af0A, bfA, af0B, bfB, af1, acc);
        tile_body(t + 1, lds, sC, rowAoff, rowBoff, off, ldsT,
                  gA0, gA1, gB0, gB1, af0B, bfB, af0A, bfA, af1, acc);
    }

    // C/D (16x16): col = lane&15, row = quad*4 + reg  [dtype-independent]
    float sxv[8][4];
    #pragma unroll
    for (int i = 0; i < 8; ++i) {
        const int row0 = mBase + wr * 128 + i * 16 + quad * 4;
        #pragma unroll
        for (int r = 0; r < 4; ++r)
            sxv[i][r] = Sx[row0 + r];
    }
    #pragma unroll
    for (int j = 0; j < 4; ++j) {
        const int col = nBase + wc * 64 + j * 16 + r16;
        const float s    = scales[col];
        const float c128 = (float)(128 - zp[col]);
        const float bv   = bias[col];
        #pragma unroll
        for (int i = 0; i < 8; ++i) {
            const int row0 = mBase + wr * 128 + i * 16 + quad * 4;
            #pragma unroll
            for (int r = 0; r < 4; ++r)
                C[(size_t)(row0 + r) * N_DIM + col] =
                    s * (XQ_INV * (float)acc[i][j][r] + c128 * sxv[i][r]) + bv;
        }
    }
}

// ---- fallback (ws too small): plain fp32 tiled GEMM ----
__global__ __launch_bounds__(256) void gemm_fb(
    const float* __restrict__ X, const int* __restrict__ Q,
    const float* __restrict__ SC, const int* __restrict__ ZP,
    const float* __restrict__ BI, float* __restrict__ C)
{
    __shared__ float Xs[64][17];
    __shared__ float Ws[64][17];
    const int tx = threadIdx.x & 15, ty = threadIdx.x >> 4;
    const int m0 = blockIdx.y * 64, n0 = blockIdx.x * 64;
    float acc[4][4] = {};
    for (int k0 = 0; k0 < K_DIM; k0 += 16) {
        for (int t = threadIdx.x; t < 64 * 16; t += 256) {
            const int r = t >> 4, c = t & 15;
            Xs[r][c] = X[(size_t)(m0 + r) * K_DIM + k0 + c];
            const int n = n0 + r;
            Ws[r][c] = (float)(Q[(size_t)n * K_DIM + k0 + c] - ZP[n]);
        }
        __syncthreads();
        #pragma unroll
        for (int kk = 0; kk < 16; ++kk) {
            float a[4], b[4];
            #pragma unroll
            for (int i = 0; i < 4; ++i) a[i] = Xs[ty * 4 + i][kk];
            #pragma unroll
            for (int j = 0; j < 4; ++j) b[j] = Ws[tx * 4 + j][kk];
            #pragma unroll
            for (int i = 0; i < 4; ++i)
                #pragma unroll
                for (int j = 0; j < 4; ++j)
                    acc[i][j] += a[i] * b[j];
        }
        __syncthreads();
    }
    #pragma unroll
    for (int j = 0; j < 4; ++j) {
        const int n = n0 + tx * 4 + j;
        const float s = SC[n], bv = BI[n];
        #pragma unroll
        for (int i = 0; i < 4; ++i)
            C[(size_t)(m0 + ty * 4 + i) * N_DIM + n] = acc[i][j] * s + bv;
    }
}

extern "C" void kernel_launch(void* const* d_in, const int* in_sizes, int n_in,
                              void* d_out, int out_size, void* d_ws, size_t ws_size,
                              hipStream_t stream) {
    const float* x  = (const float*)d_in[0];
    const int*   qw = (const int*)d_in[1];
    const float* sc = (const float*)d_in[2];
    const int*   zp = (const int*)d_in[3];
    const float* bi = (const float*)d_in[4];
    float* out = (float*)d_out;

    const size_t MK = (size_t)M_DIM * K_DIM;           // 16 Mi elems
    const size_t need = MK * 2 + M_DIM * sizeof(float); // 32 MiB + 16 KiB

    if (ws_size >= need) {
        char*  xq = (char*)d_ws;                // 16 MiB int8
        char*  qp = xq + MK;                    // 16 MiB int8
        float* Sx = (float*)(qp + MK);          // 16 KiB fp32
        prep_k<<<8192, 256, 0, stream>>>((const float4*)x, (const int4*)qw,
                                         (unsigned*)xq, (unsigned*)qp, Sx);
        gemm_i8<<<dim3(256), dim3(512), 98304, stream>>>(xq, qp, sc, zp, bi,
                                                         Sx, out);
    } else {
        gemm_fb<<<dim3(64, 64), 256, 0, stream>>>(x, qw, sc, zp, bi, out);
    }
}

// Round 3
// 247.819 us; speedup vs baseline: 1.0136x; 1.0136x over previous
//
#include <hip/hip_runtime.h>
#include <cstdint>

// Y[m,n] = scale[n]*sum_k x[m,k]*(q[n,k]-zp[n]) + bias[n];  M=N=K=4096.
// int8 path: q' = q-128 (int8, exact); xq = round(x*127/6) clamped (int8).
// Y = scale_n*( sx*acc[m,n] + (128-zp_n)*Sx[m] ) + bias_n,
//   acc = sum xq*q' (EXACT int32 via mfma_i32_16x16x64_i8), Sx = exact fp32
//   row-sum of x. Only error: x quantization.
//
// R3: fix LDS bank conflicts introduced in R2. 64-B rows: even rows all
//   start at bank 0, odd at bank 16, so the XOR swizzle must be injective
//   across same-parity rows: phys chunk = c ^ ((row>>1)&3)  (NOT row&3).
//   Each 8-lane group of a ds_read_b128 now covers all 32 banks exactly
//   once. Staging source permutation updated to the same involution.
//   Schedule unchanged from R2 (read-ahead + counted vmcnt/lgkmcnt).

#define M_DIM 4096
#define N_DIM 4096
#define K_DIM 4096

typedef int v4i __attribute__((ext_vector_type(4)));

#define XQ_F 21.1666667f      // 127/6
#define XQ_INV 0.0472440945f  // 6/127

static __device__ __forceinline__ void load_lds16(const void* g, void* l) {
    __builtin_amdgcn_global_load_lds(
        (__attribute__((address_space(1))) void*)(uintptr_t)g,
        (__attribute__((address_space(3))) void*)(uint32_t)(uintptr_t)l,
        16, 0, 0);
}

static __device__ __forceinline__ int q8(float v) {
    float r = rintf(v * XQ_F);
    r = fmaxf(-127.f, fminf(127.f, r));
    return (int)r;
}
static __device__ __forceinline__ unsigned pack4(int a, int b, int c, int d) {
    return (unsigned)(a & 255) | ((unsigned)(b & 255) << 8) |
           ((unsigned)(c & 255) << 16) | ((unsigned)(d & 255) << 24);
}

// ---- prep: block b<4096 -> x row b (quantize + exact rowsum);
//            b>=4096 -> q row b-4096 (q-128 -> int8). 16 elems/thread.
__global__ __launch_bounds__(256) void prep_k(const float4* __restrict__ x,
                                              const int4* __restrict__ q,
                                              unsigned* __restrict__ xq,
                                              unsigned* __restrict__ qp,
                                              float* __restrict__ Sx) {
    const int tid = threadIdx.x;
    if (blockIdx.x < 4096) {
        const int m = blockIdx.x;
        const float4* row = x + (size_t)m * 1024;
        unsigned* orow = xq + (size_t)m * 1024;
        float s = 0.f;
        #pragma unroll
        for (int i = 0; i < 4; ++i) {
            const int idx = tid + 256 * i;
            const float4 v = row[idx];
            s += v.x + v.y + v.z + v.w;
            orow[idx] = pack4(q8(v.x), q8(v.y), q8(v.z), q8(v.w));
        }
        #pragma unroll
        for (int off = 32; off > 0; off >>= 1)
            s += __shfl_down(s, off);
        __shared__ float red[4];
        if ((tid & 63) == 0) red[tid >> 6] = s;
        __syncthreads();
        if (tid == 0) Sx[m] = red[0] + red[1] + red[2] + red[3];
    } else {
        const int n = blockIdx.x - 4096;
        const int4* row = q + (size_t)n * 1024;
        unsigned* orow = qp + (size_t)n * 1024;
        #pragma unroll
        for (int i = 0; i < 4; ++i) {
            const int idx = tid + 256 * i;
            const int4 v = row[idx];
            orow[idx] = pack4(v.x - 128, v.y - 128, v.z - 128, v.w - 128);
        }
    }
}

// LDS slot layout (32 KiB per slot, 3 slots):
//   A[256 rows x 64 B] at slot+0, B[256 x 64] at slot+16384.
//   Row = 64 B = 4 x 16B chunks; XOR swizzle: (row, logical chunk c) at
//   byte row*64 + ((c ^ ((row>>1)&3)) * 16). With 64-B rows, even rows
//   start at bank 0 and odd rows at bank 16; XOR-ing (row>>1)&3 makes
//   every 8 consecutive lanes of a wave ds_read_b128 cover all 32 banks
//   exactly once (enumerated: banks 0,16,4,20,8,24,12,28 x4B each).
//   Staging dest flat (tid*16, global_load_lds requirement); global
//   source chunk pre-permuted with the same involution.
//
// Per-tile schedule (t: 0..63, slot = t%3):
//  W0: barrier | read af1 (A rows 64-127 of wave) | stage A rounds of t+2
//      | lgkm(4) [drains af0/bf] | 16 MFMA (af0,bf -> acc[0..3][*])
//  W1: vmcnt(2) [t+1 landed; t+2's A-rounds still in flight] | barrier
//      | read af0n/bfn of t+1 | stage B rounds of t+2 | lgkm(8) [drains af1]
//      | 16 MFMA (af1,bf -> acc[4..7][*])
__device__ __forceinline__ void tile_body(
    int t, char* lds, int& sC,
    int rowAoff, int rowBoff, int off, int ldsT,
    const char*& gA0, const char*& gA1,
    const char*& gB0, const char*& gB1,
    v4i (&af0)[4], v4i (&bf)[4],
    v4i (&af0n)[4], v4i (&bfn)[4],
    v4i (&af1)[4], v4i (&acc)[8][4])
{
    const int sN = (sC == 65536) ? 0 : sC + 32768;   // slot of t+1
    const int sS = (sN == 65536) ? 0 : sN + 32768;   // slot of t+2 (= t-1, freed)

    // ---------------- W0 ----------------
    __builtin_amdgcn_s_barrier();
    #pragma unroll
    for (int i = 0; i < 4; ++i)
        af1[i] = *(const v4i*)(lds + sC + rowAoff + (i + 4) * 1024 + off);
    if (t < 62) {
        load_lds16(gA0, lds + sS +    0 + ldsT);
        load_lds16(gA1, lds + sS + 8192 + ldsT);
    }
    asm volatile("s_waitcnt lgkmcnt(4)" ::: "memory");
    __builtin_amdgcn_sched_barrier(0);
    __builtin_amdgcn_s_setprio(1);
    #pragma unroll
    for (int i = 0; i < 4; ++i)
        #pragma unroll
        for (int j = 0; j < 4; ++j)
            acc[i][j] = __builtin_amdgcn_mfma_i32_16x16x64_i8(
                af0[i], bf[j], acc[i][j], 0, 0, 0);
    __builtin_amdgcn_s_setprio(0);

    // ---------------- W1 ----------------
    if (t < 62) asm volatile("s_waitcnt vmcnt(2)" ::: "memory");
    else        asm volatile("s_waitcnt vmcnt(0)" ::: "memory");
    __builtin_amdgcn_s_barrier();
    if (t < 63) {
        #pragma unroll
        for (int i = 0; i < 4; ++i)
            af0n[i] = *(const v4i*)(lds + sN + rowAoff + i * 1024 + off);
        #pragma unroll
        for (int j = 0; j < 4; ++j)
            bfn[j] = *(const v4i*)(lds + sN + 16384 + rowBoff + j * 1024 + off);
    }
    if (t < 62) {
        load_lds16(gB0, lds + sS + 16384 + ldsT);
        load_lds16(gB1, lds + sS + 24576 + ldsT);
        gA0 += 64; gA1 += 64; gB0 += 64; gB1 += 64;
    }
    if (t < 63) asm volatile("s_waitcnt lgkmcnt(8)" ::: "memory");
    else        asm volatile("s_waitcnt lgkmcnt(0)" ::: "memory");
    __builtin_amdgcn_sched_barrier(0);
    __builtin_amdgcn_s_setprio(1);
    #pragma unroll
    for (int i = 0; i < 4; ++i)
        #pragma unroll
        for (int j = 0; j < 4; ++j)
            acc[i + 4][j] = __builtin_amdgcn_mfma_i32_16x16x64_i8(
                af1[i], bf[j], acc[i + 4][j], 0, 0, 0);
    __builtin_amdgcn_s_setprio(0);
    sC = sN;
}

__global__ __launch_bounds__(512, 2) void gemm_i8(
    const char* __restrict__ A, const char* __restrict__ B,
    const float* __restrict__ scales, const int* __restrict__ zp,
    const float* __restrict__ bias, const float* __restrict__ Sx,
    float* __restrict__ C)
{
    extern __shared__ char lds[];   // 98304 = 3 x (A 16K + B 16K)

    const int tid  = threadIdx.x;
    const int lane = tid & 63;
    const int wave = tid >> 6;
    const int wr = wave >> 2;        // 0..1 over M (128 rows each)
    const int wc = wave & 3;         // 0..3 over N (64 cols each)

    // XCD swizzle: 16x16 tile grid; XCD x -> 4(M) x 8(N) tile rectangle
    // (A 4 MiB + B 8 MiB footprint per XCD). Bijective for 256 blocks.
    const int bid = blockIdx.x;
    const int xcd = bid & 7;
    const int loc = bid >> 3;            // 0..31
    const int tileM = (xcd & 3) * 4 + (loc & 3);
    const int tileN = (xcd >> 2) * 8 + (loc >> 2);
    const int mBase = tileM * 256;
    const int nBase = tileN * 256;

    // staging: thread tid -> row tid>>2, phys chunk tid&3; global source
    // logical chunk = (tid&3) ^ ((row>>1)&3) = (tid&3) ^ ((tid>>3)&3)
    const int rowR = tid >> 2;                        // 0..127
    const int lcS  = ((tid & 3) ^ ((tid >> 3) & 3)) * 16;   // bytes
    const char* gA0 = A + (size_t)(mBase +   0 + rowR) * K_DIM + lcS;
    const char* gA1 = A + (size_t)(mBase + 128 + rowR) * K_DIM + lcS;
    const char* gB0 = B + (size_t)(nBase +   0 + rowR) * K_DIM + lcS;
    const char* gB1 = B + (size_t)(nBase + 128 + rowR) * K_DIM + lcS;
    const int ldsT = tid * 16;

    // frag reads: row stride 64 B; logical K-chunk = quad,
    // phys = quad ^ ((row>>1)&3); row = 16*blk + r16 -> (row>>1)&3 =
    // (r16>>1)&3 (multiple-of-16 components vanish).
    const int quad = lane >> 4;
    const int r16  = lane & 15;
    const int off  = (quad ^ ((r16 >> 1) & 3)) * 16;
    const int rowAoff = (wr * 128 + r16) * 64;   // + i*1024 (16-row blocks)
    const int rowBoff = (wc *  64 + r16) * 64;   // + j*1024, region +16384

    v4i acc[8][4];
    #pragma unroll
    for (int i = 0; i < 8; ++i)
        #pragma unroll
        for (int j = 0; j < 4; ++j)
            acc[i][j] = v4i{0, 0, 0, 0};

    // ---- prologue: stage tile0 -> slot0, tile1 -> slot1 ----
    load_lds16(gA0, lds +     0 + ldsT);
    load_lds16(gA1, lds +  8192 + ldsT);
    load_lds16(gB0, lds + 16384 + ldsT);
    load_lds16(gB1, lds + 24576 + ldsT);
    gA0 += 64; gA1 += 64; gB0 += 64; gB1 += 64;
    load_lds16(gA0, lds + 32768 +     0 + ldsT);
    load_lds16(gA1, lds + 32768 +  8192 + ldsT);
    load_lds16(gB0, lds + 32768 + 16384 + ldsT);
    load_lds16(gB1, lds + 32768 + 24576 + ldsT);
    gA0 += 64; gA1 += 64; gB0 += 64; gB1 += 64;
    asm volatile("s_waitcnt vmcnt(4)" ::: "memory");   // tile0 landed
    __builtin_amdgcn_s_barrier();

    v4i af0A[4], bfA[4], af0B[4], bfB[4], af1[4];
    #pragma unroll
    for (int i = 0; i < 4; ++i)
        af0A[i] = *(const v4i*)(lds + rowAoff + i * 1024 + off);
    #pragma unroll
    for (int j = 0; j < 4; ++j)
        bfA[j] = *(const v4i*)(lds + 16384 + rowBoff + j * 1024 + off);

    int sC = 0;
    for (int t = 0; t < 64; t += 2) {
        tile_body(t,     lds, sC, rowAoff, rowBoff, off, ldsT,
                  gA0, gA1, gB0, gB1, af0A, bfA, af0B, bfB, af1, acc);
        tile_body(t + 1, lds, sC, rowAoff, rowBoff, off, ldsT,
                  gA0, gA1, gB0, gB1, af0B, bfB, af0A, bfA, af1, acc);
    }

    // C/D (16x16): col = lane&15, row = quad*4 + reg  [dtype-independent]
    float sxv[8][4];
    #pragma unroll
    for (int i = 0; i < 8; ++i) {
        const int row0 = mBase + wr * 128 + i * 16 + quad * 4;
        #pragma unroll
        for (int r = 0; r < 4; ++r)
            sxv[i][r] = Sx[row0 + r];
    }
    #pragma unroll
    for (int j = 0; j < 4; ++j) {
        const int col = nBase + wc * 64 + j * 16 + r16;
        const float s    = scales[col];
        const float c128 = (float)(128 - zp[col]);
        const float bv   = bias[col];
        #pragma unroll
        for (int i = 0; i < 8; ++i) {
            const int row0 = mBase + wr * 128 + i * 16 + quad * 4;
            #pragma unroll
            for (int r = 0; r < 4; ++r)
                C[(size_t)(row0 + r) * N_DIM + col] =
                    s * (XQ_INV * (float)acc[i][j][r] + c128 * sxv[i][r]) + bv;
        }
    }
}

// ---- fallback (ws too small): plain fp32 tiled GEMM ----
__global__ __launch_bounds__(256) void gemm_fb(
    const float* __restrict__ X, const int* __restrict__ Q,
    const float* __restrict__ SC, const int* __restrict__ ZP,
    const float* __restrict__ BI, float* __restrict__ C)
{
    __shared__ float Xs[64][17];
    __shared__ float Ws[64][17];
    const int tx = threadIdx.x & 15, ty = threadIdx.x >> 4;
    const int m0 = blockIdx.y * 64, n0 = blockIdx.x * 64;
    float acc[4][4] = {};
    for (int k0 = 0; k0 < K_DIM; k0 += 16) {
        for (int t = threadIdx.x; t < 64 * 16; t += 256) {
            const int r = t >> 4, c = t & 15;
            Xs[r][c] = X[(size_t)(m0 + r) * K_DIM + k0 + c];
            const int n = n0 + r;
            Ws[r][c] = (float)(Q[(size_t)n * K_DIM + k0 + c] - ZP[n]);
        }
        __syncthreads();
        #pragma unroll
        for (int kk = 0; kk < 16; ++kk) {
            float a[4], b[4];
            #pragma unroll
            for (int i = 0; i < 4; ++i) a[i] = Xs[ty * 4 + i][kk];
            #pragma unroll
            for (int j = 0; j < 4; ++j) b[j] = Ws[tx * 4 + j][kk];
            #pragma unroll
            for (int i = 0; i < 4; ++i)
                #pragma unroll
                for (int j = 0; j < 4; ++j)
                    acc[i][j] += a[i] * b[j];
        }
        __syncthreads();
    }
    #pragma unroll
    for (int j = 0; j < 4; ++j) {
        const int n = n0 + tx * 4 + j;
        const float s = SC[n], bv = BI[n];
        #pragma unroll
        for (int i = 0; i < 4; ++i)
            C[(size_t)(m0 + ty * 4 + i) * N_DIM + n] = acc[i][j] * s + bv;
    }
}

extern "C" void kernel_launch(void* const* d_in, const int* in_sizes, int n_in,
                              void* d_out, int out_size, void* d_ws, size_t ws_size,
                              hipStream_t stream) {
    const float* x  = (const float*)d_in[0];
    const int*   qw = (const int*)d_in[1];
    const float* sc = (const float*)d_in[2];
    const int*   zp = (const int*)d_in[3];
    const float* bi = (const float*)d_in[4];
    float* out = (float*)d_out;

    const size_t MK = (size_t)M_DIM * K_DIM;           // 16 Mi elems
    const size_t need = MK * 2 + M_DIM * sizeof(float); // 32 MiB + 16 KiB

    if (ws_size >= need) {
        char*  xq = (char*)d_ws;                // 16 MiB int8
        char*  qp = xq + MK;                    // 16 MiB int8
        float* Sx = (float*)(qp + MK);          // 16 KiB fp32
        prep_k<<<8192, 256, 0, stream>>>((const float4*)x, (const int4*)qw,
                                         (unsigned*)xq, (unsigned*)qp, Sx);
        gemm_i8<<<dim3(256), dim3(512), 98304, stream>>>(xq, qp, sc, zp, bi,
                                                         Sx, out);
    } else {
        gemm_fb<<<dim3(64, 64), 256, 0, stream>>>(x, qw, sc, zp, bi, out);
    }
}